// Round 8
// baseline (297.600 us; speedup 1.0000x reference)
//
#include <hip/hip_runtime.h>

// GraphNet interaction network. Edge MLP via bf16 MFMA (fp32 accum).
// V7: V4b structure (1 receiver / 256-thread block, barrier-free tile loop)
// but B2/B3 weight fragments held in REGISTERS (loaded once per wave from
// global, L1-resident) instead of re-read from LDS every tile. Removes the
// 18.4 KB wsmem + staging barrier + 16 KB/tile of LDS reads. LDS 45.5->26.7KB;
// VGPR ~76->~155 (occupancy stays 3 waves/SIMD, now VGPR-capped).
#define BB   32
#define NN   188
#define PP   16
#define HID  128
#define HH2  64
#define DE   5
#define DO   6
#define NT   5
#define ROWS_O (BB*NN)
#define RT   32
#define KO   (PP+DE)

typedef __attribute__((ext_vector_type(8))) short short8;   // 8 bf16 = 4 VGPRs
typedef __attribute__((ext_vector_type(4))) float float4_;

__device__ __forceinline__ short f2bf(float v) {            // RNE (prep only)
    union { float f; unsigned u; } a; a.f = v;
    unsigned r = a.u + 0x7fff + ((a.u >> 16) & 1);
    return (short)(r >> 16);
}
// relu + round bits: hi16 of result is bf16(max(v,0)) (round-nearest)
__device__ __forceinline__ unsigned r2u(float v) {
    v = v > 0.f ? v : 0.f;
    return __float_as_uint(v) + 0x8000u;
}
// (hi16(hi)<<16) | hi16(lo)
__device__ __forceinline__ unsigned pack_hi16(unsigned hi, unsigned lo) {
    return __builtin_amdgcn_perm(hi, lo, 0x07060302);
}

// workspace layout (shorts)
#define XB_OFF    0                        // bf16 [32][188][24]
#define XB_ELTS   (BB*NN*24)               // 144384
#define W1T_OFF   (XB_OFF + XB_ELTS)       // bf16 [128 n][40 k]
#define W1T_ELTS  (HID*40)                 // 5120
#define W2S_OFF   (W1T_OFF + W1T_ELTS)     // swizzled frags [16][64 lanes][8]
#define W2S_ELTS  (16*64*8)                // 8192
#define W3S_OFF   (W2S_OFF + W2S_ELTS)     // swizzled frags [2][64][8]
#define W3S_ELTS  (2*64*8)                 // 1024
#define SHORT_TOTAL (W3S_OFF + W3S_ELTS)

// pi-inverse for the k-pairing permutation (range 128 for W2, 64 for W3):
// pi(k): t=k>>4, n=k&15 -> (t>>1)*32 + n*2 + (t&1). Inverse:
__device__ __forceinline__ int pinv(int pk) {
    return ((pk >> 5) * 2 + (pk & 1)) * 16 + ((pk & 31) >> 1);
}

__global__ void prep_kernel(const float* __restrict__ x,
                            const float* __restrict__ w1,
                            const float* __restrict__ w2,
                            const float* __restrict__ w3,
                            short* __restrict__ ws)
{
    const int i = blockIdx.x * blockDim.x + threadIdx.x;
    const int stride = gridDim.x * blockDim.x;
    for (int idx = i; idx < BB*NN*PP; idx += stride) {       // x -> xb
        int row = idx >> 4, k = idx & 15;
        ws[XB_OFF + row*24 + k] = f2bf(x[idx]);
    }
    for (int idx = i; idx < 32*HID; idx += stride) {         // w1 [k][n] -> [n][40]
        int k = idx >> 7, n = idx & 127;
        ws[W1T_OFF + n*40 + k] = f2bf(w1[idx]);
    }
    for (int idx = i; idx < W2S_ELTS; idx += stride) {       // w2 -> swizzled frags
        int f = idx >> 9;            // frag = t*4+s
        int l = (idx >> 3) & 63;     // lane
        int e = idx & 7;
        int t = f >> 2, s = f & 3;
        int q = l >> 4, n16 = l & 15;
        int pk = s*32 + q*8 + e;
        int k = pinv(pk);
        int n = t*16 + n16;
        ws[W2S_OFF + idx] = f2bf(w2[k*HH2 + n]);
    }
    for (int idx = i; idx < W3S_ELTS; idx += stride) {       // w3 -> swizzled frags
        int s = idx >> 9;
        int l = (idx >> 3) & 63;
        int e = idx & 7;
        int q = l >> 4, n16 = l & 15;
        int pk = s*32 + q*8 + e;
        int k = pinv(pk);
        ws[W3S_OFF + idx] = (n16 < DE) ? f2bf(w3[k*DE + n16]) : (short)0;
    }
}

// ---------------------------------------------------------------------------
// Edge MLP: 32 -> 128 relu -> 64 relu -> 5 relu, summed over 187 edges of one
// (batch, receiver). 256 threads = 4 waves; 3 row-tiles of 16 per wave.
// ---------------------------------------------------------------------------
__global__ __launch_bounds__(256, 3)
void edge_mfma_kernel(const short* __restrict__ ws_s,
                      const float* __restrict__ b1,
                      const float* __restrict__ b2,
                      const float* __restrict__ b3,
                      float* __restrict__ ebar)
{
    const short* xb  = ws_s + XB_OFF;
    const short* w1t = ws_s + W1T_OFF;
    const short* w2g = ws_s + W2S_OFF;
    const short* w3g = ws_s + W3S_OFF;

    __shared__ __align__(16) unsigned h1d[4][16*68];  // per-wave [row][68 dw]
    __shared__ __align__(16) unsigned h2d[4][16*36];  // per-wave [row][36 dw]
    __shared__ float red[4][DE];

    const int bi   = blockIdx.x;           // b*188 + recv
    const int b    = bi / NN;
    const int recv = bi - b*NN;
    const int tid  = threadIdx.x;
    const int wave = tid >> 6;
    const int lane = tid & 63;
    const int n16  = lane & 15;
    const int q    = lane >> 4;

    // stationary weight fragments in registers (global, L1/L2-hot)
    short8 B1[8];
    #pragma unroll
    for (int t = 0; t < 8; ++t)
        B1[t] = *(const short8*)(w1t + (t*16 + n16)*40 + q*8);
    short8 B2[16];
    #pragma unroll
    for (int f = 0; f < 16; ++f)
        B2[f] = *(const short8*)(w2g + f*512 + lane*8);
    short8 B3[2];
    #pragma unroll
    for (int s = 0; s < 2; ++s)
        B3[s] = *(const short8*)(w3g + s*512 + lane*8);

    float bias1[8];
    #pragma unroll
    for (int t = 0; t < 8; ++t) bias1[t] = b1[t*16 + n16];
    float bias2[4];
    #pragma unroll
    for (int t = 0; t < 4; ++t) bias2[t] = b2[t*16 + n16];
    const float bias3 = (n16 < DE) ? b3[n16] : 0.f;

    const short* xrow = xb + b*(NN*24);
    unsigned* h1w = &h1d[wave][0];
    unsigned* h2w = &h2d[wave][0];
    const short* h1r = (const short*)&h1d[wave][0];
    const short* h2r = (const short*)&h2d[wave][0];

    float acc[4] = {0.f, 0.f, 0.f, 0.f};

    #pragma unroll
    for (int ti = 0; ti < 3; ++ti) {
        const int rowbase = (wave*3 + ti) * 16;
        // A frag: [x[recv] | x[send_r]]
        const int r = rowbase + n16;
        int send = r + (r >= recv ? 1 : 0);
        if (send > NN-1) send = NN-1;
        const int node = (q < 2) ? recv : send;
        const int koff = (q & 1) * 8;
        short8 A1 = *(const short8*)(xrow + node*24 + koff);

        // ---- layer 1: 8 N-tiles as 4 pairs; pack (t,t+1) lane-locally ----
        #pragma unroll
        for (int m = 0; m < 4; ++m) {
            float4_ Ca = (float4_){bias1[2*m],   bias1[2*m],   bias1[2*m],   bias1[2*m]};
            float4_ Cb = (float4_){bias1[2*m+1], bias1[2*m+1], bias1[2*m+1], bias1[2*m+1]};
            Ca = __builtin_amdgcn_mfma_f32_16x16x32_bf16(A1, B1[2*m],   Ca, 0, 0, 0);
            Cb = __builtin_amdgcn_mfma_f32_16x16x32_bf16(A1, B1[2*m+1], Cb, 0, 0, 0);
            #pragma unroll
            for (int rg = 0; rg < 4; ++rg)
                h1w[(q*4+rg)*68 + m*16 + n16] = pack_hi16(r2u(Cb[rg]), r2u(Ca[rg]));
        }

        // ---- layer 2: A frags from wave-private LDS; B frags from registers ----
        short8 A2[4];
        #pragma unroll
        for (int s = 0; s < 4; ++s)
            A2[s] = *(const short8*)(h1r + n16*136 + s*32 + q*8);
        #pragma unroll
        for (int m = 0; m < 2; ++m) {
            float4_ Ca = (float4_){bias2[2*m],   bias2[2*m],   bias2[2*m],   bias2[2*m]};
            float4_ Cb = (float4_){bias2[2*m+1], bias2[2*m+1], bias2[2*m+1], bias2[2*m+1]};
            #pragma unroll
            for (int s = 0; s < 4; ++s) {
                Ca = __builtin_amdgcn_mfma_f32_16x16x32_bf16(A2[s], B2[(2*m)*4+s],   Ca, 0, 0, 0);
                Cb = __builtin_amdgcn_mfma_f32_16x16x32_bf16(A2[s], B2[(2*m+1)*4+s], Cb, 0, 0, 0);
            }
            #pragma unroll
            for (int rg = 0; rg < 4; ++rg)
                h2w[(q*4+rg)*36 + m*16 + n16] = pack_hi16(r2u(Cb[rg]), r2u(Ca[rg]));
        }

        // ---- layer 3: N=16 (5 used), K=64 ----
        float4_ C3 = (float4_){bias3, bias3, bias3, bias3};
        #pragma unroll
        for (int s = 0; s < 2; ++s) {
            short8 A3 = *(const short8*)(h2r + n16*72 + s*32 + q*8);
            C3 = __builtin_amdgcn_mfma_f32_16x16x32_bf16(A3, B3[s], C3, 0, 0, 0);
        }
        #pragma unroll
        for (int rg = 0; rg < 4; ++rg) {
            const int rowid = rowbase + q*4 + rg;
            float e = C3[rg];
            e = e > 0.f ? e : 0.f;
            acc[rg] += (rowid < NN-1) ? e : 0.f;
        }
    }

    float s = (acc[0] + acc[1]) + (acc[2] + acc[3]);
    s += __shfl_xor(s, 16, 64);
    s += __shfl_xor(s, 32, 64);
    if (lane < DE) red[wave][lane] = s;
    __syncthreads();
    if (wave == 0 && lane < DE) {
        float tot = red[0][lane] + red[1][lane] + red[2][lane] + red[3][lane];
        ebar[bi*DE + lane] = tot;
    }
}

// ---------------------------------------------------------------------------
// Object MLP (unchanged): [x(16)|Ebar(5)] -> 128 -> 64 -> 6 relu
// ---------------------------------------------------------------------------
__global__ __launch_bounds__(512)
void obj_mlp_kernel(const float* __restrict__ x, const float* __restrict__ ebar,
                    const float* __restrict__ w1, const float* __restrict__ b1,
                    const float* __restrict__ w2, const float* __restrict__ b2,
                    const float* __restrict__ w3, const float* __restrict__ b3,
                    float* __restrict__ o_out)
{
    __shared__ float sW[HID*HH2];
    __shared__ float sB1[HID];
    __shared__ float sB2[HH2];
    __shared__ float sCin[RT*KO];
    __shared__ float sH1[RT*HID];
    __shared__ float sH2t[HH2*(RT+1)];
    const int tid = threadIdx.x;
    const int rbase = blockIdx.x * RT;

    for (int i = tid; i < KO*HID; i += 512) sW[i] = w1[i];
    if (tid < HID) sB1[tid] = b1[tid];
    else if (tid < HID+HH2) sB2[tid-HID] = b2[tid-HID];
    for (int i = tid; i < RT*KO; i += 512) {
        int r = i / KO, k = i - r*KO;
        int gr = rbase + r;
        int b = gr / NN;
        int node = gr - b*NN;
        sCin[i] = (k < PP) ? x[(b*NN+node)*PP + k]
                           : ebar[(b*NN+node)*DE + (k-PP)];
    }
    __syncthreads();

    {
        const int j = tid & (HID-1);
        const int g = tid >> 7;
        float w[KO];
        #pragma unroll
        for (int k = 0; k < KO; ++k) w[k] = sW[k*HID + j];
        const float bj = sB1[j];
        #pragma unroll
        for (int rr = 0; rr < 8; ++rr) {
            const int r = g*8 + rr;
            const float* e = &sCin[r*KO];
            float a0=0.f,a1=0.f,a2=0.f;
            #pragma unroll
            for (int k = 0; k < KO; k += 3) {
                a0 += w[k+0]*e[k+0];
                a1 += w[k+1]*e[k+1];
                a2 += w[k+2]*e[k+2];
            }
            float v = a0+a1+a2+bj;
            sH1[r*HID + j] = v > 0.f ? v : 0.f;
        }
    }
    __syncthreads();
    for (int i = tid; i < HID*HH2; i += 512) sW[i] = w2[i];
    __syncthreads();

    {
        const int j = tid & (HH2-1);
        const int g = tid >> 6;
        float acc[4];
        #pragma unroll
        for (int rr = 0; rr < 4; ++rr) acc[rr] = sB2[j];
        #pragma unroll
        for (int kc = 0; kc < HID; kc += 32) {
            float w[32];
            #pragma unroll
            for (int kk = 0; kk < 32; ++kk) w[kk] = sW[(kc+kk)*HH2 + j];
            #pragma unroll
            for (int rr = 0; rr < 4; ++rr) {
                const float* h = &sH1[(g*4+rr)*HID + kc];
                float a0=0.f,a1=0.f,a2=0.f,a3=0.f;
                #pragma unroll
                for (int kk = 0; kk < 32; kk += 4) {
                    a0 += w[kk+0]*h[kk+0];
                    a1 += w[kk+1]*h[kk+1];
                    a2 += w[kk+2]*h[kk+2];
                    a3 += w[kk+3]*h[kk+3];
                }
                acc[rr] += (a0+a1)+(a2+a3);
            }
        }
        #pragma unroll
        for (int rr = 0; rr < 4; ++rr) {
            float v = acc[rr];
            sH2t[j*(RT+1) + (g*4+rr)] = v > 0.f ? v : 0.f;
        }
    }
    __syncthreads();

    if (tid < RT*DO) {
        const int r = tid & (RT-1);
        const int c = tid >> 5;
        float a0=0.f,a1=0.f,a2=0.f,a3=0.f;
        #pragma unroll
        for (int k = 0; k < HH2; k += 4) {
            a0 += sH2t[(k+0)*(RT+1)+r]*w3[(k+0)*DO+c];
            a1 += sH2t[(k+1)*(RT+1)+r]*w3[(k+1)*DO+c];
            a2 += sH2t[(k+2)*(RT+1)+r]*w3[(k+2)*DO+c];
            a3 += sH2t[(k+3)*(RT+1)+r]*w3[(k+3)*DO+c];
        }
        float v = (a0+a1)+(a2+a3) + b3[c];
        v = v > 0.f ? v : 0.f;
        int gr = rbase + r;
        int b = gr / NN;
        int node = gr - b*NN;
        o_out[b*(NN*DO) + node*DO + c] = v;
    }
}

// ---------------------------------------------------------------------------
// Classifier (unchanged): 1128 -> 128 relu -> 64 relu -> 5
// ---------------------------------------------------------------------------
__global__ __launch_bounds__(256)
void fc_kernel(const float* __restrict__ o_in,
               const float* __restrict__ w1, const float* __restrict__ b1,
               const float* __restrict__ w2, const float* __restrict__ b2,
               const float* __restrict__ w3, const float* __restrict__ b3,
               float* __restrict__ out)
{
    __shared__ __align__(16) float s_in[NN*DO];
    __shared__ float s_p[256];
    __shared__ float s_h1[HID];
    __shared__ float s_h2[HH2];
    const int b = blockIdx.x, tid = threadIdx.x;

    for (int i = tid; i < NN*DO; i += 256) s_in[i] = o_in[b*(NN*DO) + i];
    __syncthreads();

    {
        const int j = tid & (HID-1);
        const int h = tid >> 7;
        const float4* s4 = (const float4*)&s_in[h*564];
        const float* wbase = w1 + (size_t)(h*564)*HID + j;
        float a0=0.f,a1=0.f,a2=0.f,a3=0.f;
        #pragma unroll 4
        for (int i = 0; i < 141; ++i) {
            float4 v = s4[i];
            const float* wp = wbase + (size_t)i*4*HID;
            a0 += v.x * wp[0];
            a1 += v.y * wp[HID];
            a2 += v.z * wp[2*HID];
            a3 += v.w * wp[3*HID];
        }
        s_p[tid] = (a0+a1)+(a2+a3);
    }
    __syncthreads();
    if (tid < HID) {
        float v = s_p[tid] + s_p[tid+HID] + b1[tid];
        s_h1[tid] = v > 0.f ? v : 0.f;
    }
    __syncthreads();

    {
        const int j = tid & (HH2-1);
        const int q = tid >> 6;
        float acc = 0.f;
        #pragma unroll
        for (int kk = 0; kk < 32; ++kk) {
            int k = q*32 + kk;
            acc += s_h1[k] * w2[k*HH2 + j];
        }
        s_p[tid] = acc;
    }
    __syncthreads();
    if (tid < HH2) {
        float v = s_p[tid] + s_p[tid+64] + s_p[tid+128] + s_p[tid+192] + b2[tid];
        s_h2[tid] = v > 0.f ? v : 0.f;
    }
    __syncthreads();

    if (tid < NT) {
        float acc = b3[tid];
        #pragma unroll
        for (int k = 0; k < HH2; ++k)
            acc += s_h2[k] * w3[k*NT + tid];
        out[b*NT + tid] = acc;
    }
}

extern "C" void kernel_launch(void* const* d_in, const int* in_sizes, int n_in,
                              void* d_out, int out_size, void* d_ws, size_t ws_size,
                              hipStream_t stream) {
    (void)in_sizes; (void)n_in; (void)out_size; (void)ws_size;
    const float* x     = (const float*)d_in[0];
    const float* fr1_w = (const float*)d_in[1];
    const float* fr1_b = (const float*)d_in[2];
    const float* fr2_w = (const float*)d_in[3];
    const float* fr2_b = (const float*)d_in[4];
    const float* fr3_w = (const float*)d_in[5];
    const float* fr3_b = (const float*)d_in[6];
    const float* fo1_w = (const float*)d_in[7];
    const float* fo1_b = (const float*)d_in[8];
    const float* fo2_w = (const float*)d_in[9];
    const float* fo2_b = (const float*)d_in[10];
    const float* fo3_w = (const float*)d_in[11];
    const float* fo3_b = (const float*)d_in[12];
    const float* fc1_w = (const float*)d_in[13];
    const float* fc1_b = (const float*)d_in[14];
    const float* fc2_w = (const float*)d_in[15];
    const float* fc2_b = (const float*)d_in[16];
    const float* fc3_w = (const float*)d_in[17];
    const float* fc3_b = (const float*)d_in[18];

    short* ws_s = (short*)d_ws;
    size_t fbase = ((size_t)SHORT_TOTAL*2 + 15) & ~(size_t)15;
    float* ebar = (float*)((char*)d_ws + fbase);            // [32][188][5]
    float* o_ws = ebar + BB*NN*DE;                          // [32][188][6]

    prep_kernel<<<128, 256, 0, stream>>>(x, fr1_w, fr2_w, fr3_w, ws_s);
    edge_mfma_kernel<<<BB*NN, 256, 0, stream>>>(ws_s, fr1_b, fr2_b, fr3_b, ebar);
    obj_mlp_kernel<<<ROWS_O/RT, 512, 0, stream>>>(
        x, ebar, fo1_w, fo1_b, fo2_w, fo2_b, fo3_w, fo3_b, o_ws);
    fc_kernel<<<BB, 256, 0, stream>>>(
        o_ws, fc1_w, fc1_b, fc2_w, fc2_b, fc3_w, fc3_b, (float*)d_out);
}

// Round 9
// 187.751 us; speedup vs baseline: 1.5851x; 1.5851x over previous
//
#include <hip/hip_runtime.h>

// GraphNet interaction network. Edge MLP via bf16 MFMA (fp32 accum).
// V8: R5 structure (verified 62us) + register/LDS hybrid for W2:
// frags 0-7 in registers (loaded once from global), frags 8-15 + W3 in
// block LDS (10 KB staged). Targets <=128 VGPR (4 waves/SIMD) AND
// 36.9 KB LDS (4 blocks/CU) -> 16 waves/CU cap vs R5's 12, with W2 LDS
// re-read traffic halved. NO min-waves launch-bounds clause (V7's forced
// 84-VGPR cap spilled B2 to scratch -> 264 MB/dispatch fetch, 172us).
#define BB   32
#define NN   188
#define PP   16
#define HID  128
#define HH2  64
#define DE   5
#define DO   6
#define NT   5
#define ROWS_O (BB*NN)
#define RT   32
#define KO   (PP+DE)

typedef __attribute__((ext_vector_type(8))) short short8;   // 8 bf16 = 4 VGPRs
typedef __attribute__((ext_vector_type(4))) float float4_;

__device__ __forceinline__ short f2bf(float v) {            // RNE (prep only)
    union { float f; unsigned u; } a; a.f = v;
    unsigned r = a.u + 0x7fff + ((a.u >> 16) & 1);
    return (short)(r >> 16);
}
// relu + round bits: hi16 of result is bf16(max(v,0)) (round-nearest)
__device__ __forceinline__ unsigned r2u(float v) {
    v = v > 0.f ? v : 0.f;
    return __float_as_uint(v) + 0x8000u;
}
// (hi16(hi)<<16) | hi16(lo)
__device__ __forceinline__ unsigned pack_hi16(unsigned hi, unsigned lo) {
    return __builtin_amdgcn_perm(hi, lo, 0x07060302);
}

// workspace layout (shorts)
#define XB_OFF    0                        // bf16 [32][188][24]
#define XB_ELTS   (BB*NN*24)               // 144384
#define W1T_OFF   (XB_OFF + XB_ELTS)       // bf16 [128 n][40 k]
#define W1T_ELTS  (HID*40)                 // 5120
#define W2S_OFF   (W1T_OFF + W1T_ELTS)     // swizzled frags [16][64 lanes][8]
#define W2S_ELTS  (16*64*8)                // 8192
#define W3S_OFF   (W2S_OFF + W2S_ELTS)     // swizzled frags [2][64][8]
#define W3S_ELTS  (2*64*8)                 // 1024
#define SHORT_TOTAL (W3S_OFF + W3S_ELTS)
// LDS-staged region: W2 frags 8..15 + W3 = 4096 + 1024 shorts = 10240 B
#define STAGE_SHORT_OFF (W2S_OFF + 8*512)
#define STAGE_UINT4     ((8*512 + W3S_ELTS) * 2 / 16)   // 640

// pi-inverse for the k-pairing permutation (range 128 for W2, 64 for W3):
// pi(k): t=k>>4, n=k&15 -> (t>>1)*32 + n*2 + (t&1). Inverse:
__device__ __forceinline__ int pinv(int pk) {
    return ((pk >> 5) * 2 + (pk & 1)) * 16 + ((pk & 31) >> 1);
}

__global__ void prep_kernel(const float* __restrict__ x,
                            const float* __restrict__ w1,
                            const float* __restrict__ w2,
                            const float* __restrict__ w3,
                            short* __restrict__ ws)
{
    const int i = blockIdx.x * blockDim.x + threadIdx.x;
    const int stride = gridDim.x * blockDim.x;
    for (int idx = i; idx < BB*NN*PP; idx += stride) {       // x -> xb
        int row = idx >> 4, k = idx & 15;
        ws[XB_OFF + row*24 + k] = f2bf(x[idx]);
    }
    for (int idx = i; idx < 32*HID; idx += stride) {         // w1 [k][n] -> [n][40]
        int k = idx >> 7, n = idx & 127;
        ws[W1T_OFF + n*40 + k] = f2bf(w1[idx]);
    }
    for (int idx = i; idx < W2S_ELTS; idx += stride) {       // w2 -> swizzled frags
        int f = idx >> 9;            // frag = t*4+s
        int l = (idx >> 3) & 63;     // lane
        int e = idx & 7;
        int t = f >> 2, s = f & 3;
        int q = l >> 4, n16 = l & 15;
        int pk = s*32 + q*8 + e;
        int k = pinv(pk);
        int n = t*16 + n16;
        ws[W2S_OFF + idx] = f2bf(w2[k*HH2 + n]);
    }
    for (int idx = i; idx < W3S_ELTS; idx += stride) {       // w3 -> swizzled frags
        int s = idx >> 9;
        int l = (idx >> 3) & 63;
        int e = idx & 7;
        int q = l >> 4, n16 = l & 15;
        int pk = s*32 + q*8 + e;
        int k = pinv(pk);
        ws[W3S_OFF + idx] = (n16 < DE) ? f2bf(w3[k*DE + n16]) : (short)0;
    }
}

// ---------------------------------------------------------------------------
// Edge MLP: 32 -> 128 relu -> 64 relu -> 5 relu, summed over 187 edges of one
// (batch, receiver). 256 threads = 4 waves; 3 row-tiles of 16 per wave.
// ---------------------------------------------------------------------------
__global__ __launch_bounds__(256)
void edge_mfma_kernel(const short* __restrict__ ws_s,
                      const float* __restrict__ b1,
                      const float* __restrict__ b2,
                      const float* __restrict__ b3,
                      float* __restrict__ ebar)
{
    const short* xb  = ws_s + XB_OFF;
    const short* w1t = ws_s + W1T_OFF;
    const short* w2g = ws_s + W2S_OFF;

    __shared__ __align__(16) unsigned wsmem[2560];    // W2 frags 8..15 + W3 (10240 B)
    __shared__ __align__(16) unsigned h1d[4][16*68];  // per-wave [row][68 dw]
    __shared__ __align__(16) unsigned h2d[4][16*36];  // per-wave [row][36 dw]
    __shared__ float red[4][DE];

    const int bi   = blockIdx.x;           // b*188 + recv
    const int b    = bi / NN;
    const int recv = bi - b*NN;
    const int tid  = threadIdx.x;
    const int wave = tid >> 6;
    const int lane = tid & 63;
    const int n16  = lane & 15;
    const int q    = lane >> 4;

    // stage W2 frags 8..15 + W3 into LDS: 640 uint4
    {
        const uint4* src = (const uint4*)(ws_s + STAGE_SHORT_OFF);
        uint4* dst = (uint4*)wsmem;
        #pragma unroll
        for (int i = 0; i < 3; ++i) {
            int idx = tid + i*256;
            if (idx < STAGE_UINT4) dst[idx] = src[idx];
        }
    }

    // register-resident weight fragments (global, L2-hot)
    short8 B1[8];
    #pragma unroll
    for (int t = 0; t < 8; ++t)
        B1[t] = *(const short8*)(w1t + (t*16 + n16)*40 + q*8);
    short8 B2r[8];                                    // W2 frags 0..7
    #pragma unroll
    for (int f = 0; f < 8; ++f)
        B2r[f] = *(const short8*)(w2g + f*512 + lane*8);

    float bias1[8];
    #pragma unroll
    for (int t = 0; t < 8; ++t) bias1[t] = b1[t*16 + n16];
    float bias2[4];
    #pragma unroll
    for (int t = 0; t < 4; ++t) bias2[t] = b2[t*16 + n16];
    const float bias3 = (n16 < DE) ? b3[n16] : 0.f;

    __syncthreads();    // wsmem ready

    const short* w2l = (const short*)wsmem;           // frag f(8..15): [(f-8)*512 + lane*8]
    const short* w3l = (const short*)wsmem + 4096;    // frag s: [s*512 + lane*8]
    short8 B3[2];
    #pragma unroll
    for (int s = 0; s < 2; ++s)
        B3[s] = *(const short8*)(w3l + s*512 + lane*8);

    const short* xrow = xb + b*(NN*24);
    unsigned* h1w = &h1d[wave][0];
    unsigned* h2w = &h2d[wave][0];
    const short* h1r = (const short*)&h1d[wave][0];
    const short* h2r = (const short*)&h2d[wave][0];

    float acc[4] = {0.f, 0.f, 0.f, 0.f};

    #pragma unroll
    for (int ti = 0; ti < 3; ++ti) {
        const int rowbase = (wave*3 + ti) * 16;
        // A frag: [x[recv] | x[send_r]]
        const int r = rowbase + n16;
        int send = r + (r >= recv ? 1 : 0);
        if (send > NN-1) send = NN-1;
        const int node = (q < 2) ? recv : send;
        const int koff = (q & 1) * 8;
        short8 A1 = *(const short8*)(xrow + node*24 + koff);

        // ---- layer 1: 8 N-tiles as 4 pairs; pack (t,t+1) lane-locally ----
        #pragma unroll
        for (int m = 0; m < 4; ++m) {
            float4_ Ca = (float4_){bias1[2*m],   bias1[2*m],   bias1[2*m],   bias1[2*m]};
            float4_ Cb = (float4_){bias1[2*m+1], bias1[2*m+1], bias1[2*m+1], bias1[2*m+1]};
            Ca = __builtin_amdgcn_mfma_f32_16x16x32_bf16(A1, B1[2*m],   Ca, 0, 0, 0);
            Cb = __builtin_amdgcn_mfma_f32_16x16x32_bf16(A1, B1[2*m+1], Cb, 0, 0, 0);
            #pragma unroll
            for (int rg = 0; rg < 4; ++rg)
                h1w[(q*4+rg)*68 + m*16 + n16] = pack_hi16(r2u(Cb[rg]), r2u(Ca[rg]));
        }

        // ---- layer 2: A frags from wave-private LDS;
        //      m=0 -> B from registers (frags 0..7), m=1 -> B from LDS (8..15) ----
        short8 A2[4];
        #pragma unroll
        for (int s = 0; s < 4; ++s)
            A2[s] = *(const short8*)(h1r + n16*136 + s*32 + q*8);
        {   // m = 0: t=0 (f0..3) and t=1 (f4..7), register frags
            float4_ Ca = (float4_){bias2[0], bias2[0], bias2[0], bias2[0]};
            float4_ Cb = (float4_){bias2[1], bias2[1], bias2[1], bias2[1]};
            #pragma unroll
            for (int s = 0; s < 4; ++s) {
                Ca = __builtin_amdgcn_mfma_f32_16x16x32_bf16(A2[s], B2r[s],   Ca, 0, 0, 0);
                Cb = __builtin_amdgcn_mfma_f32_16x16x32_bf16(A2[s], B2r[4+s], Cb, 0, 0, 0);
            }
            #pragma unroll
            for (int rg = 0; rg < 4; ++rg)
                h2w[(q*4+rg)*36 + n16] = pack_hi16(r2u(Cb[rg]), r2u(Ca[rg]));
        }
        {   // m = 1: t=2 (f8..11) and t=3 (f12..15), LDS frags
            float4_ Ca = (float4_){bias2[2], bias2[2], bias2[2], bias2[2]};
            float4_ Cb = (float4_){bias2[3], bias2[3], bias2[3], bias2[3]};
            #pragma unroll
            for (int s = 0; s < 4; ++s) {
                short8 Ba = *(const short8*)(w2l + (s)*512   + lane*8);      // f=8+s
                short8 Bb = *(const short8*)(w2l + (4+s)*512 + lane*8);      // f=12+s
                Ca = __builtin_amdgcn_mfma_f32_16x16x32_bf16(A2[s], Ba, Ca, 0, 0, 0);
                Cb = __builtin_amdgcn_mfma_f32_16x16x32_bf16(A2[s], Bb, Cb, 0, 0, 0);
            }
            #pragma unroll
            for (int rg = 0; rg < 4; ++rg)
                h2w[(q*4+rg)*36 + 16 + n16] = pack_hi16(r2u(Cb[rg]), r2u(Ca[rg]));
        }

        // ---- layer 3: N=16 (5 used), K=64 ----
        float4_ C3 = (float4_){bias3, bias3, bias3, bias3};
        #pragma unroll
        for (int s = 0; s < 2; ++s) {
            short8 A3 = *(const short8*)(h2r + n16*72 + s*32 + q*8);
            C3 = __builtin_amdgcn_mfma_f32_16x16x32_bf16(A3, B3[s], C3, 0, 0, 0);
        }
        #pragma unroll
        for (int rg = 0; rg < 4; ++rg) {
            const int rowid = rowbase + q*4 + rg;
            float e = C3[rg];
            e = e > 0.f ? e : 0.f;
            acc[rg] += (rowid < NN-1) ? e : 0.f;
        }
    }

    float s = (acc[0] + acc[1]) + (acc[2] + acc[3]);
    s += __shfl_xor(s, 16, 64);
    s += __shfl_xor(s, 32, 64);
    if (lane < DE) red[wave][lane] = s;
    __syncthreads();
    if (wave == 0 && lane < DE) {
        float tot = red[0][lane] + red[1][lane] + red[2][lane] + red[3][lane];
        ebar[bi*DE + lane] = tot;
    }
}

// ---------------------------------------------------------------------------
// Object MLP (unchanged): [x(16)|Ebar(5)] -> 128 -> 64 -> 6 relu
// ---------------------------------------------------------------------------
__global__ __launch_bounds__(512)
void obj_mlp_kernel(const float* __restrict__ x, const float* __restrict__ ebar,
                    const float* __restrict__ w1, const float* __restrict__ b1,
                    const float* __restrict__ w2, const float* __restrict__ b2,
                    const float* __restrict__ w3, const float* __restrict__ b3,
                    float* __restrict__ o_out)
{
    __shared__ float sW[HID*HH2];
    __shared__ float sB1[HID];
    __shared__ float sB2[HH2];
    __shared__ float sCin[RT*KO];
    __shared__ float sH1[RT*HID];
    __shared__ float sH2t[HH2*(RT+1)];
    const int tid = threadIdx.x;
    const int rbase = blockIdx.x * RT;

    for (int i = tid; i < KO*HID; i += 512) sW[i] = w1[i];
    if (tid < HID) sB1[tid] = b1[tid];
    else if (tid < HID+HH2) sB2[tid-HID] = b2[tid-HID];
    for (int i = tid; i < RT*KO; i += 512) {
        int r = i / KO, k = i - r*KO;
        int gr = rbase + r;
        int b = gr / NN;
        int node = gr - b*NN;
        sCin[i] = (k < PP) ? x[(b*NN+node)*PP + k]
                           : ebar[(b*NN+node)*DE + (k-PP)];
    }
    __syncthreads();

    {
        const int j = tid & (HID-1);
        const int g = tid >> 7;
        float w[KO];
        #pragma unroll
        for (int k = 0; k < KO; ++k) w[k] = sW[k*HID + j];
        const float bj = sB1[j];
        #pragma unroll
        for (int rr = 0; rr < 8; ++rr) {
            const int r = g*8 + rr;
            const float* e = &sCin[r*KO];
            float a0=0.f,a1=0.f,a2=0.f;
            #pragma unroll
            for (int k = 0; k < KO; k += 3) {
                a0 += w[k+0]*e[k+0];
                a1 += w[k+1]*e[k+1];
                a2 += w[k+2]*e[k+2];
            }
            float v = a0+a1+a2+bj;
            sH1[r*HID + j] = v > 0.f ? v : 0.f;
        }
    }
    __syncthreads();
    for (int i = tid; i < HID*HH2; i += 512) sW[i] = w2[i];
    __syncthreads();

    {
        const int j = tid & (HH2-1);
        const int g = tid >> 6;
        float acc[4];
        #pragma unroll
        for (int rr = 0; rr < 4; ++rr) acc[rr] = sB2[j];
        #pragma unroll
        for (int kc = 0; kc < HID; kc += 32) {
            float w[32];
            #pragma unroll
            for (int kk = 0; kk < 32; ++kk) w[kk] = sW[(kc+kk)*HH2 + j];
            #pragma unroll
            for (int rr = 0; rr < 4; ++rr) {
                const float* h = &sH1[(g*4+rr)*HID + kc];
                float a0=0.f,a1=0.f,a2=0.f,a3=0.f;
                #pragma unroll
                for (int kk = 0; kk < 32; kk += 4) {
                    a0 += w[kk+0]*h[kk+0];
                    a1 += w[kk+1]*h[kk+1];
                    a2 += w[kk+2]*h[kk+2];
                    a3 += w[kk+3]*h[kk+3];
                }
                acc[rr] += (a0+a1)+(a2+a3);
            }
        }
        #pragma unroll
        for (int rr = 0; rr < 4; ++rr) {
            float v = acc[rr];
            sH2t[j*(RT+1) + (g*4+rr)] = v > 0.f ? v : 0.f;
        }
    }
    __syncthreads();

    if (tid < RT*DO) {
        const int r = tid & (RT-1);
        const int c = tid >> 5;
        float a0=0.f,a1=0.f,a2=0.f,a3=0.f;
        #pragma unroll
        for (int k = 0; k < HH2; k += 4) {
            a0 += sH2t[(k+0)*(RT+1)+r]*w3[(k+0)*DO+c];
            a1 += sH2t[(k+1)*(RT+1)+r]*w3[(k+1)*DO+c];
            a2 += sH2t[(k+2)*(RT+1)+r]*w3[(k+2)*DO+c];
            a3 += sH2t[(k+3)*(RT+1)+r]*w3[(k+3)*DO+c];
        }
        float v = (a0+a1)+(a2+a3) + b3[c];
        v = v > 0.f ? v : 0.f;
        int gr = rbase + r;
        int b = gr / NN;
        int node = gr - b*NN;
        o_out[b*(NN*DO) + node*DO + c] = v;
    }
}

// ---------------------------------------------------------------------------
// Classifier (unchanged): 1128 -> 128 relu -> 64 relu -> 5
// ---------------------------------------------------------------------------
__global__ __launch_bounds__(256)
void fc_kernel(const float* __restrict__ o_in,
               const float* __restrict__ w1, const float* __restrict__ b1,
               const float* __restrict__ w2, const float* __restrict__ b2,
               const float* __restrict__ w3, const float* __restrict__ b3,
               float* __restrict__ out)
{
    __shared__ __align__(16) float s_in[NN*DO];
    __shared__ float s_p[256];
    __shared__ float s_h1[HID];
    __shared__ float s_h2[HH2];
    const int b = blockIdx.x, tid = threadIdx.x;

    for (int i = tid; i < NN*DO; i += 256) s_in[i] = o_in[b*(NN*DO) + i];
    __syncthreads();

    {
        const int j = tid & (HID-1);
        const int h = tid >> 7;
        const float4* s4 = (const float4*)&s_in[h*564];
        const float* wbase = w1 + (size_t)(h*564)*HID + j;
        float a0=0.f,a1=0.f,a2=0.f,a3=0.f;
        #pragma unroll 4
        for (int i = 0; i < 141; ++i) {
            float4 v = s4[i];
            const float* wp = wbase + (size_t)i*4*HID;
            a0 += v.x * wp[0];
            a1 += v.y * wp[HID];
            a2 += v.z * wp[2*HID];
            a3 += v.w * wp[3*HID];
        }
        s_p[tid] = (a0+a1)+(a2+a3);
    }
    __syncthreads();
    if (tid < HID) {
        float v = s_p[tid] + s_p[tid+HID] + b1[tid];
        s_h1[tid] = v > 0.f ? v : 0.f;
    }
    __syncthreads();

    {
        const int j = tid & (HH2-1);
        const int q = tid >> 6;
        float acc = 0.f;
        #pragma unroll
        for (int kk = 0; kk < 32; ++kk) {
            int k = q*32 + kk;
            acc += s_h1[k] * w2[k*HH2 + j];
        }
        s_p[tid] = acc;
    }
    __syncthreads();
    if (tid < HH2) {
        float v = s_p[tid] + s_p[tid+64] + s_p[tid+128] + s_p[tid+192] + b2[tid];
        s_h2[tid] = v > 0.f ? v : 0.f;
    }
    __syncthreads();

    if (tid < NT) {
        float acc = b3[tid];
        #pragma unroll
        for (int k = 0; k < HH2; ++k)
            acc += s_h2[k] * w3[k*NT + tid];
        out[b*NT + tid] = acc;
    }
}

extern "C" void kernel_launch(void* const* d_in, const int* in_sizes, int n_in,
                              void* d_out, int out_size, void* d_ws, size_t ws_size,
                              hipStream_t stream) {
    (void)in_sizes; (void)n_in; (void)out_size; (void)ws_size;
    const float* x     = (const float*)d_in[0];
    const float* fr1_w = (const float*)d_in[1];
    const float* fr1_b = (const float*)d_in[2];
    const float* fr2_w = (const float*)d_in[3];
    const float* fr2_b = (const float*)d_in[4];
    const float* fr3_w = (const float*)d_in[5];
    const float* fr3_b = (const float*)d_in[6];
    const float* fo1_w = (const float*)d_in[7];
    const float* fo1_b = (const float*)d_in[8];
    const float* fo2_w = (const float*)d_in[9];
    const float* fo2_b = (const float*)d_in[10];
    const float* fo3_w = (const float*)d_in[11];
    const float* fo3_b = (const float*)d_in[12];
    const float* fc1_w = (const float*)d_in[13];
    const float* fc1_b = (const float*)d_in[14];
    const float* fc2_w = (const float*)d_in[15];
    const float* fc2_b = (const float*)d_in[16];
    const float* fc3_w = (const float*)d_in[17];
    const float* fc3_b = (const float*)d_in[18];

    short* ws_s = (short*)d_ws;
    size_t fbase = ((size_t)SHORT_TOTAL*2 + 15) & ~(size_t)15;
    float* ebar = (float*)((char*)d_ws + fbase);            // [32][188][5]
    float* o_ws = ebar + BB*NN*DE;                          // [32][188][6]

    prep_kernel<<<128, 256, 0, stream>>>(x, fr1_w, fr2_w, fr3_w, ws_s);
    edge_mfma_kernel<<<BB*NN, 256, 0, stream>>>(ws_s, fr1_b, fr2_b, fr3_b, ebar);
    obj_mlp_kernel<<<ROWS_O/RT, 512, 0, stream>>>(
        x, ebar, fo1_w, fo1_b, fo2_w, fo2_b, fo3_w, fo3_b, o_ws);
    fc_kernel<<<BB, 256, 0, stream>>>(
        o_ws, fc1_w, fc1_b, fc2_w, fc2_b, fc3_w, fc3_b, (float*)d_out);
}

// Round 10
// 173.419 us; speedup vs baseline: 1.7161x; 1.0826x over previous
//
#include <hip/hip_runtime.h>

// GraphNet interaction network. Edge MLP via bf16 MFMA (fp32 accum).
// V9: operand-swapped edge MLP — edges on N, neurons on M. Layer-l C output
// (col=edge, row=q*4+rg) IS the layer-(l+1) B-fragment under a k-permutation
// baked into W2/W3 at prep: MFMA-k (q,j) <-> neuron 32s + (j<4? q*4+j :
// 16+q*4+(j-4)). Inter-layer transform = lane-local relu+pack in registers;
// h1/h2 LDS round-trips (24 writes + 6 b128 reads/tile) deleted. W2 frags in
// 16KB LDS; W1/W3/biases in regs.
#define BB   32
#define NN   188
#define PP   16
#define HID  128
#define HH2  64
#define DE   5
#define DO   6
#define NT   5
#define ROWS_O (BB*NN)
#define RT   32
#define KO   (PP+DE)

typedef __attribute__((ext_vector_type(8))) short short8;     // 8 bf16 = 4 VGPRs
typedef __attribute__((ext_vector_type(4))) float float4_;
typedef __attribute__((ext_vector_type(4))) unsigned uint4_;

__device__ __forceinline__ short f2bf(float v) {              // RNE (prep only)
    union { float f; unsigned u; } a; a.f = v;
    unsigned r = a.u + 0x7fff + ((a.u >> 16) & 1);
    return (short)(r >> 16);
}
// relu + round bits: hi16 of result is bf16(max(v,0)) (round-nearest)
__device__ __forceinline__ unsigned r2u(float v) {
    v = v > 0.f ? v : 0.f;
    return __float_as_uint(v) + 0x8000u;
}
// (hi16(hi)<<16) | hi16(lo)
__device__ __forceinline__ unsigned pack_hi16(unsigned hi, unsigned lo) {
    return __builtin_amdgcn_perm(hi, lo, 0x07060302);
}

// workspace layout (shorts)
#define XB_OFF    0                        // bf16 [32][188][24]
#define XB_ELTS   (BB*NN*24)               // 144384
#define W1T_OFF   (XB_OFF + XB_ELTS)       // bf16 [128 n][40 k]
#define W1T_ELTS  (HID*40)                 // 5120
#define W2S_OFF   (W1T_OFF + W1T_ELTS)     // A-frags [16 f][64 lanes][8]
#define W2S_ELTS  (16*64*8)                // 8192
#define W3S_OFF   (W2S_OFF + W2S_ELTS)     // A-frags [2 s][64 lanes][8]
#define W3S_ELTS  (2*64*8)                 // 1024
#define SHORT_TOTAL (W3S_OFF + W3S_ELTS)

// MFMA-k position (q, e) -> neuron offset within a 32-block
__device__ __forceinline__ int kmap(int q, int e) {
    return (e < 4) ? (q*4 + e) : (16 + q*4 + (e - 4));
}

__global__ void prep_kernel(const float* __restrict__ x,
                            const float* __restrict__ w1,
                            const float* __restrict__ w2,
                            const float* __restrict__ w3,
                            short* __restrict__ ws)
{
    const int i = blockIdx.x * blockDim.x + threadIdx.x;
    const int stride = gridDim.x * blockDim.x;
    for (int idx = i; idx < BB*NN*PP; idx += stride) {       // x -> xb
        int row = idx >> 4, k = idx & 15;
        ws[XB_OFF + row*24 + k] = f2bf(x[idx]);
    }
    for (int idx = i; idx < 32*HID; idx += stride) {         // w1 [k][n] -> [n][40]
        int k = idx >> 7, n = idx & 127;
        ws[W1T_OFF + n*40 + k] = f2bf(w1[idx]);
    }
    for (int idx = i; idx < W2S_ELTS; idx += stride) {       // w2 -> A-frags
        int f = idx >> 9;            // frag = tt*4 + s
        int l = (idx >> 3) & 63;     // lane
        int e = idx & 7;
        int tt = f >> 2, s = f & 3;
        int q = l >> 4, n16 = l & 15;
        int k = 32*s + kmap(q, e);
        int n = tt*16 + n16;
        ws[W2S_OFF + idx] = f2bf(w2[k*HH2 + n]);
    }
    for (int idx = i; idx < W3S_ELTS; idx += stride) {       // w3 -> A-frags
        int s2 = idx >> 9;
        int l = (idx >> 3) & 63;
        int e = idx & 7;
        int q = l >> 4, n16 = l & 15;
        int k = 32*s2 + kmap(q, e);
        ws[W3S_OFF + idx] = (n16 < DE) ? f2bf(w3[k*DE + n16]) : (short)0;
    }
}

// ---------------------------------------------------------------------------
// Edge MLP: 32 -> 128 relu -> 64 relu -> 5 relu, summed over 187 edges of one
// (batch, receiver). 256 threads = 4 waves; 3 edge-tiles of 16 per wave.
// Edges on N: C layouts chain into B-fragments with zero data movement.
// ---------------------------------------------------------------------------
__global__ __launch_bounds__(256)
void edge_mfma_kernel(const short* __restrict__ ws_s,
                      const float* __restrict__ b1,
                      const float* __restrict__ b2,
                      const float* __restrict__ b3,
                      float* __restrict__ ebar)
{
    const short* xb  = ws_s + XB_OFF;
    const short* w1t = ws_s + W1T_OFF;
    const short* w3g = ws_s + W3S_OFF;

    __shared__ __align__(16) unsigned wsmem[4096];   // W2 A-frags, 16 KB
    __shared__ __align__(16) float sB1[HID];         // b1 copy for C-init reads
    __shared__ float red[4][16];

    const int bi   = blockIdx.x;           // b*188 + recv
    const int b    = bi / NN;
    const int recv = bi - b*NN;
    const int tid  = threadIdx.x;
    const int wave = tid >> 6;
    const int lane = tid & 63;
    const int n16  = lane & 15;
    const int q    = lane >> 4;

    // stage W2 frags: 16384 B = 1024 uint4, exactly 4 per thread
    {
        const uint4* src = (const uint4*)(ws_s + W2S_OFF);
        uint4* dst = (uint4*)wsmem;
        #pragma unroll
        for (int i = 0; i < 4; ++i) dst[tid + i*256] = src[tid + i*256];
    }
    if (tid < HID) sB1[tid] = b1[tid];

    // register-resident: W1 A-frags, W3 A-frags, biases
    short8 W1f[8];
    #pragma unroll
    for (int t = 0; t < 8; ++t)
        W1f[t] = *(const short8*)(w1t + (t*16 + n16)*40 + q*8);
    short8 W3f[2];
    #pragma unroll
    for (int s = 0; s < 2; ++s)
        W3f[s] = *(const short8*)(w3g + s*512 + lane*8);
    float4_ bias2v[4];
    #pragma unroll
    for (int tt = 0; tt < 4; ++tt)
        bias2v[tt] = *(const float4_*)(b2 + tt*16 + q*4);
    float4_ bias3r;
    #pragma unroll
    for (int rg = 0; rg < 4; ++rg) {
        int o = q*4 + rg;
        bias3r[rg] = (o < DE) ? b3[o] : 0.f;
    }

    __syncthreads();    // wsmem + sB1 ready

    const short* w2l = (const short*)wsmem;      // frag f: [f*512 + lane*8]
    const short* xrow = xb + b*(NN*24);

    float acc[4] = {0.f, 0.f, 0.f, 0.f};

    #pragma unroll
    for (int ti = 0; ti < 3; ++ti) {
        const int rowbase = (wave*3 + ti) * 16;
        const int e = rowbase + n16;             // this lane's edge (all q share)
        int send = e + (e >= recv ? 1 : 0);
        if (send > NN-1) send = NN-1;            // clamp padding rows
        const int node = (q < 2) ? recv : send;
        short8 E1 = *(const short8*)(xrow + node*24 + (q & 1)*8);   // B-frag

        // layer-2 accumulators, bias-initialized (C operand, no copies)
        float4_ C2[4];
        #pragma unroll
        for (int tt = 0; tt < 4; ++tt) C2[tt] = bias2v[tt];

        // ---- fused layer 1 + layer 2, per 32-neuron step s ----
        #pragma unroll
        for (int s = 0; s < 4; ++s) {
            float4_ cb0 = *(const float4_*)(sB1 + (2*s)*16   + q*4);
            float4_ cb1 = *(const float4_*)(sB1 + (2*s+1)*16 + q*4);
            float4_ Ca = __builtin_amdgcn_mfma_f32_16x16x32_bf16(W1f[2*s],   E1, cb0, 0, 0, 0);
            float4_ Cb = __builtin_amdgcn_mfma_f32_16x16x32_bf16(W1f[2*s+1], E1, cb1, 0, 0, 0);
            // H1 B-frag: lane-local relu+pack (C rows q*4+rg ARE k slots q*8+j)
            uint4_ dv = (uint4_){ pack_hi16(r2u(Ca[1]), r2u(Ca[0])),
                                  pack_hi16(r2u(Ca[3]), r2u(Ca[2])),
                                  pack_hi16(r2u(Cb[1]), r2u(Cb[0])),
                                  pack_hi16(r2u(Cb[3]), r2u(Cb[2])) };
            short8 Bf = __builtin_bit_cast(short8, dv);
            #pragma unroll
            for (int tt = 0; tt < 4; ++tt) {
                short8 A2 = *(const short8*)(w2l + (tt*4 + s)*512 + lane*8);
                C2[tt] = __builtin_amdgcn_mfma_f32_16x16x32_bf16(A2, Bf, C2[tt], 0, 0, 0);
            }
        }

        // ---- layer 3: H2 B-frags lane-local from C2 ----
        float4_ C3 = bias3r;
        #pragma unroll
        for (int s2 = 0; s2 < 2; ++s2) {
            float4_ Cc = C2[2*s2], Cd = C2[2*s2+1];
            uint4_ dv = (uint4_){ pack_hi16(r2u(Cc[1]), r2u(Cc[0])),
                                  pack_hi16(r2u(Cc[3]), r2u(Cc[2])),
                                  pack_hi16(r2u(Cd[1]), r2u(Cd[0])),
                                  pack_hi16(r2u(Cd[3]), r2u(Cd[2])) };
            short8 B3f = __builtin_bit_cast(short8, dv);
            C3 = __builtin_amdgcn_mfma_f32_16x16x32_bf16(W3f[s2], B3f, C3, 0, 0, 0);
        }
        // relu + per-lane edge mask + accumulate (lane holds o=q*4+rg for edge e)
        const bool ok = (e < NN-1);
        #pragma unroll
        for (int rg = 0; rg < 4; ++rg) {
            float v = C3[rg];
            v = v > 0.f ? v : 0.f;
            acc[rg] += ok ? v : 0.f;
        }
    }

    // reduce over the 16 edge-columns (n16 direction)
    #pragma unroll
    for (int rg = 0; rg < 4; ++rg) {
        acc[rg] += __shfl_xor(acc[rg], 1);
        acc[rg] += __shfl_xor(acc[rg], 2);
        acc[rg] += __shfl_xor(acc[rg], 4);
        acc[rg] += __shfl_xor(acc[rg], 8);
    }
    if (n16 == 0) {
        #pragma unroll
        for (int rg = 0; rg < 4; ++rg) red[wave][q*4 + rg] = acc[rg];
    }
    __syncthreads();
    if (wave == 0 && lane < DE) {
        float tot = red[0][lane] + red[1][lane] + red[2][lane] + red[3][lane];
        ebar[bi*DE + lane] = tot;
    }
}

// ---------------------------------------------------------------------------
// Object MLP (unchanged): [x(16)|Ebar(5)] -> 128 -> 64 -> 6 relu
// ---------------------------------------------------------------------------
__global__ __launch_bounds__(512)
void obj_mlp_kernel(const float* __restrict__ x, const float* __restrict__ ebar,
                    const float* __restrict__ w1, const float* __restrict__ b1,
                    const float* __restrict__ w2, const float* __restrict__ b2,
                    const float* __restrict__ w3, const float* __restrict__ b3,
                    float* __restrict__ o_out)
{
    __shared__ float sW[HID*HH2];
    __shared__ float sB1[HID];
    __shared__ float sB2[HH2];
    __shared__ float sCin[RT*KO];
    __shared__ float sH1[RT*HID];
    __shared__ float sH2t[HH2*(RT+1)];
    const int tid = threadIdx.x;
    const int rbase = blockIdx.x * RT;

    for (int i = tid; i < KO*HID; i += 512) sW[i] = w1[i];
    if (tid < HID) sB1[tid] = b1[tid];
    else if (tid < HID+HH2) sB2[tid-HID] = b2[tid-HID];
    for (int i = tid; i < RT*KO; i += 512) {
        int r = i / KO, k = i - r*KO;
        int gr = rbase + r;
        int b = gr / NN;
        int node = gr - b*NN;
        sCin[i] = (k < PP) ? x[(b*NN+node)*PP + k]
                           : ebar[(b*NN+node)*DE + (k-PP)];
    }
    __syncthreads();

    {
        const int j = tid & (HID-1);
        const int g = tid >> 7;
        float w[KO];
        #pragma unroll
        for (int k = 0; k < KO; ++k) w[k] = sW[k*HID + j];
        const float bj = sB1[j];
        #pragma unroll
        for (int rr = 0; rr < 8; ++rr) {
            const int r = g*8 + rr;
            const float* e = &sCin[r*KO];
            float a0=0.f,a1=0.f,a2=0.f;
            #pragma unroll
            for (int k = 0; k < KO; k += 3) {
                a0 += w[k+0]*e[k+0];
                a1 += w[k+1]*e[k+1];
                a2 += w[k+2]*e[k+2];
            }
            float v = a0+a1+a2+bj;
            sH1[r*HID + j] = v > 0.f ? v : 0.f;
        }
    }
    __syncthreads();
    for (int i = tid; i < HID*HH2; i += 512) sW[i] = w2[i];
    __syncthreads();

    {
        const int j = tid & (HH2-1);
        const int g = tid >> 6;
        float acc[4];
        #pragma unroll
        for (int rr = 0; rr < 4; ++rr) acc[rr] = sB2[j];
        #pragma unroll
        for (int kc = 0; kc < HID; kc += 32) {
            float w[32];
            #pragma unroll
            for (int kk = 0; kk < 32; ++kk) w[kk] = sW[(kc+kk)*HH2 + j];
            #pragma unroll
            for (int rr = 0; rr < 4; ++rr) {
                const float* h = &sH1[(g*4+rr)*HID + kc];
                float a0=0.f,a1=0.f,a2=0.f,a3=0.f;
                #pragma unroll
                for (int kk = 0; kk < 32; kk += 4) {
                    a0 += w[kk+0]*h[kk+0];
                    a1 += w[kk+1]*h[kk+1];
                    a2 += w[kk+2]*h[kk+2];
                    a3 += w[kk+3]*h[kk+3];
                }
                acc[rr] += (a0+a1)+(a2+a3);
            }
        }
        #pragma unroll
        for (int rr = 0; rr < 4; ++rr) {
            float v = acc[rr];
            sH2t[j*(RT+1) + (g*4+rr)] = v > 0.f ? v : 0.f;
        }
    }
    __syncthreads();

    if (tid < RT*DO) {
        const int r = tid & (RT-1);
        const int c = tid >> 5;
        float a0=0.f,a1=0.f,a2=0.f,a3=0.f;
        #pragma unroll
        for (int k = 0; k < HH2; k += 4) {
            a0 += sH2t[(k+0)*(RT+1)+r]*w3[(k+0)*DO+c];
            a1 += sH2t[(k+1)*(RT+1)+r]*w3[(k+1)*DO+c];
            a2 += sH2t[(k+2)*(RT+1)+r]*w3[(k+2)*DO+c];
            a3 += sH2t[(k+3)*(RT+1)+r]*w3[(k+3)*DO+c];
        }
        float v = (a0+a1)+(a2+a3) + b3[c];
        v = v > 0.f ? v : 0.f;
        int gr = rbase + r;
        int b = gr / NN;
        int node = gr - b*NN;
        o_out[b*(NN*DO) + node*DO + c] = v;
    }
}

// ---------------------------------------------------------------------------
// Classifier (unchanged): 1128 -> 128 relu -> 64 relu -> 5
// ---------------------------------------------------------------------------
__global__ __launch_bounds__(256)
void fc_kernel(const float* __restrict__ o_in,
               const float* __restrict__ w1, const float* __restrict__ b1,
               const float* __restrict__ w2, const float* __restrict__ b2,
               const float* __restrict__ w3, const float* __restrict__ b3,
               float* __restrict__ out)
{
    __shared__ __align__(16) float s_in[NN*DO];
    __shared__ float s_p[256];
    __shared__ float s_h1[HID];
    __shared__ float s_h2[HH2];
    const int b = blockIdx.x, tid = threadIdx.x;

    for (int i = tid; i < NN*DO; i += 256) s_in[i] = o_in[b*(NN*DO) + i];
    __syncthreads();

    {
        const int j = tid & (HID-1);
        const int h = tid >> 7;
        const float4* s4 = (const float4*)&s_in[h*564];
        const float* wbase = w1 + (size_t)(h*564)*HID + j;
        float a0=0.f,a1=0.f,a2=0.f,a3=0.f;
        #pragma unroll 4
        for (int i = 0; i < 141; ++i) {
            float4 v = s4[i];
            const float* wp = wbase + (size_t)i*4*HID;
            a0 += v.x * wp[0];
            a1 += v.y * wp[HID];
            a2 += v.z * wp[2*HID];
            a3 += v.w * wp[3*HID];
        }
        s_p[tid] = (a0+a1)+(a2+a3);
    }
    __syncthreads();
    if (tid < HID) {
        float v = s_p[tid] + s_p[tid+HID] + b1[tid];
        s_h1[tid] = v > 0.f ? v : 0.f;
    }
    __syncthreads();

    {
        const int j = tid & (HH2-1);
        const int q = tid >> 6;
        float acc = 0.f;
        #pragma unroll
        for (int kk = 0; kk < 32; ++kk) {
            int k = q*32 + kk;
            acc += s_h1[k] * w2[k*HH2 + j];
        }
        s_p[tid] = acc;
    }
    __syncthreads();
    if (tid < HH2) {
        float v = s_p[tid] + s_p[tid+64] + s_p[tid+128] + s_p[tid+192] + b2[tid];
        s_h2[tid] = v > 0.f ? v : 0.f;
    }
    __syncthreads();

    if (tid < NT) {
        float acc = b3[tid];
        #pragma unroll
        for (int k = 0; k < HH2; ++k)
            acc += s_h2[k] * w3[k*NT + tid];
        out[b*NT + tid] = acc;
    }
}

extern "C" void kernel_launch(void* const* d_in, const int* in_sizes, int n_in,
                              void* d_out, int out_size, void* d_ws, size_t ws_size,
                              hipStream_t stream) {
    (void)in_sizes; (void)n_in; (void)out_size; (void)ws_size;
    const float* x     = (const float*)d_in[0];
    const float* fr1_w = (const float*)d_in[1];
    const float* fr1_b = (const float*)d_in[2];
    const float* fr2_w = (const float*)d_in[3];
    const float* fr2_b = (const float*)d_in[4];
    const float* fr3_w = (const float*)d_in[5];
    const float* fr3_b = (const float*)d_in[6];
    const float* fo1_w = (const float*)d_in[7];
    const float* fo1_b = (const float*)d_in[8];
    const float* fo2_w = (const float*)d_in[9];
    const float* fo2_b = (const float*)d_in[10];
    const float* fo3_w = (const float*)d_in[11];
    const float* fo3_b = (const float*)d_in[12];
    const float* fc1_w = (const float*)d_in[13];
    const float* fc1_b = (const float*)d_in[14];
    const float* fc2_w = (const float*)d_in[15];
    const float* fc2_b = (const float*)d_in[16];
    const float* fc3_w = (const float*)d_in[17];
    const float* fc3_b = (const float*)d_in[18];

    short* ws_s = (short*)d_ws;
    size_t fbase = ((size_t)SHORT_TOTAL*2 + 15) & ~(size_t)15;
    float* ebar = (float*)((char*)d_ws + fbase);            // [32][188][5]
    float* o_ws = ebar + BB*NN*DE;                          // [32][188][6]

    prep_kernel<<<128, 256, 0, stream>>>(x, fr1_w, fr2_w, fr3_w, ws_s);
    edge_mfma_kernel<<<BB*NN, 256, 0, stream>>>(ws_s, fr1_b, fr2_b, fr3_b, ebar);
    obj_mlp_kernel<<<ROWS_O/RT, 512, 0, stream>>>(
        x, ebar, fo1_w, fo1_b, fo2_w, fo2_b, fo3_w, fo3_b, o_ws);
    fc_kernel<<<BB, 256, 0, stream>>>(
        o_ws, fc1_w, fc1_b, fc2_w, fc2_b, fc3_w, fc3_b, (float*)d_out);
}